// Round 13
// baseline (372.245 us; speedup 1.0000x reference)
//
#include <hip/hip_runtime.h>
#include <hip/hip_bf16.h>
#include <type_traits>
#include <cstdint>

using bf16 = __hip_bfloat16;
typedef __attribute__((ext_vector_type(8))) short bf16x8;   // MFMA A/B frag (4 VGPRs)
typedef __attribute__((ext_vector_type(4))) float f32x4;    // MFMA C/D frag

__device__ __forceinline__ float bf2f(unsigned short u) {
    union { unsigned int i; float f; } c; c.i = ((unsigned int)u) << 16; return c.f;
}

// Branchless exact-GELU: A&S 7.1.26 erf (|err|<1.5e-7, far below bf16 rounding)
__device__ __forceinline__ float gelu_f(float v) {
    float x  = v * 0.70710678118654752f;
    float ax = fabsf(x);
    float t  = __builtin_amdgcn_rcpf(1.0f + 0.3275911f * ax);
    float poly = ((((1.061405429f * t - 1.453152027f) * t + 1.421413741f) * t
                   - 0.284496736f) * t + 0.254829592f) * t;
    float erfv = 1.0f - poly * __expf(-ax * ax);
    erfv = copysignf(erfv, x);
    return 0.5f * v * (1.0f + erfv);
}

// async global->LDS, 16 B per lane; lds dest must be wave-uniform base (+lane*16)
#define GLLDS16(gp, lp)                                                          \
    __builtin_amdgcn_global_load_lds(                                            \
        (const __attribute__((address_space(1))) void*)(gp),                     \
        (__attribute__((address_space(3))) void*)(lp), 16, 0, 0)

// ---------------------------------------------------------------------------
// Fused convert+transpose: w[K][N] fp32 -> wt[N][K] bf16, 32x32 LDS tiles.
// ---------------------------------------------------------------------------
__global__ __launch_bounds__(256) void transpose_f2b(const float* __restrict__ w,
                                                     bf16* __restrict__ wt,
                                                     int K, int N) {
    __shared__ bf16 t[32][33];
    const int tid = threadIdx.x;
    const int n0 = blockIdx.x * 32, k0 = blockIdx.y * 32;
#pragma unroll
    for (int i = 0; i < 4; ++i) {
        int idx = tid + i * 256;
        int r = idx >> 5, c = idx & 31;
        t[r][c] = __float2bfloat16(w[(size_t)(k0 + r) * N + n0 + c]);
    }
    __syncthreads();
#pragma unroll
    for (int i = 0; i < 4; ++i) {
        int idx = tid + i * 256;
        int r = idx >> 5, c = idx & 31;
        wt[(size_t)(n0 + r) * K + k0 + c] = t[c][r];
    }
}

// ---------------------------------------------------------------------------
// Dual transpose: two weight matrices (shared K=1024) in ONE dispatch.
// ---------------------------------------------------------------------------
__global__ __launch_bounds__(256) void transpose2_f2b(const float* __restrict__ w0,
                                                      bf16* __restrict__ wt0,
                                                      int N0, int nb0,
                                                      const float* __restrict__ w1,
                                                      bf16* __restrict__ wt1,
                                                      int N1, int K) {
    __shared__ bf16 t[32][33];
    const int tid = threadIdx.x;
    int bx = blockIdx.x;
    const float* w; bf16* wt; int N;
    if (bx < nb0) { w = w0; wt = wt0; N = N0; }
    else          { w = w1; wt = wt1; N = N1; bx -= nb0; }
    const int n0 = bx * 32, k0 = blockIdx.y * 32;
#pragma unroll
    for (int i = 0; i < 4; ++i) {
        int idx = tid + i * 256;
        int r = idx >> 5, c = idx & 31;
        t[r][c] = __float2bfloat16(w[(size_t)(k0 + r) * N + n0 + c]);
    }
    __syncthreads();
#pragma unroll
    for (int i = 0; i < 4; ++i) {
        int idx = tid + i * 256;
        int r = idx >> 5, c = idx & 31;
        wt[(size_t)(n0 + r) * K + k0 + c] = t[c][r];
    }
}

// ---------------------------------------------------------------------------
// V pre-transpose: qkv[token][h*192+128+c] -> vtg[(b*16+h)][c][s]  (bf16)
// ---------------------------------------------------------------------------
__global__ __launch_bounds__(256) void vtrans_kernel(const bf16* __restrict__ qkv,
                                                     bf16* __restrict__ vtg) {
    __shared__ bf16 t[32][33];
    const int tid = threadIdx.x;
    const int s0 = blockIdx.x * 32, c0 = blockIdx.y * 32;
    const int bh = blockIdx.z, b = bh >> 4, h = bh & 15;
#pragma unroll
    for (int i = 0; i < 4; ++i) {
        int idx = tid + i * 256;
        int r = idx >> 5, c = idx & 31;
        t[r][c] = qkv[(size_t)(b * 2048 + s0 + r) * 3072 + h * 192 + 128 + c0 + c];
    }
    __syncthreads();
#pragma unroll
    for (int i = 0; i < 4; ++i) {
        int idx = tid + i * 256;
        int r = idx >> 5, c = idx & 31;
        vtg[((size_t)bh * 64 + c0 + r) * 2048 + s0 + c] = t[c][r];
    }
}

// ---------------------------------------------------------------------------
// LayerNorm over W=1024: one block per row, 256 threads x 4 elems.
// ---------------------------------------------------------------------------
template <typename InT>
__global__ __launch_bounds__(256) void ln_kernel(const InT* __restrict__ x,
                                                 const float* __restrict__ g,
                                                 const float* __restrict__ bta,
                                                 bf16* __restrict__ y) {
    const int row = blockIdx.x, tid = threadIdx.x;
    const size_t base = (size_t)row * 1024 + tid * 4;
    float v[4];
    if constexpr (std::is_same_v<InT, float>) {
        float4 f = *(const float4*)(x + base);
        v[0] = f.x; v[1] = f.y; v[2] = f.z; v[3] = f.w;
    } else {
        ushort4 u = *(const ushort4*)((const unsigned short*)x + base);
        v[0] = bf2f(u.x); v[1] = bf2f(u.y); v[2] = bf2f(u.z); v[3] = bf2f(u.w);
    }
    float s = v[0] + v[1] + v[2] + v[3];
    float sq = v[0]*v[0] + v[1]*v[1] + v[2]*v[2] + v[3]*v[3];
#pragma unroll
    for (int off = 32; off > 0; off >>= 1) {
        s  += __shfl_down(s, off);
        sq += __shfl_down(sq, off);
    }
    __shared__ float red[8];
    const int wave = tid >> 6, lane = tid & 63;
    if (lane == 0) { red[wave] = s; red[4 + wave] = sq; }
    __syncthreads();
    s  = red[0] + red[1] + red[2] + red[3];
    sq = red[4] + red[5] + red[6] + red[7];
    const float mu   = s * (1.0f / 1024.0f);
    const float var  = sq * (1.0f / 1024.0f) - mu * mu;
    const float rstd = rsqrtf(var + 1e-5f);
#pragma unroll
    for (int e = 0; e < 4; ++e) {
        int col = tid * 4 + e;
        float yy = (v[e] - mu) * rstd * g[col] + bta[col];
        y[base + e] = __float2bfloat16(yy);
    }
}

// ---------------------------------------------------------------------------
// GEMM: C[M,N] = A[M,K] @ B[K,N] (+bias fp32, epilogue). A,Bt bf16; Bt=[N][K].
// BM x 128 tile, BK=64, 4 waves, 16x16x32 bf16 MFMA.
// BM==128: GLLDS16 + XOR-16B-chunk swizzle + 2-phase dbuf with T4 COUNTED
//   vmcnt: raw s_barrier + vmcnt(8) keeps next-tile loads in flight ACROSS
//   the barrier (each stage = 8 GLLDS/wave; 16 outstanding steady-state;
//   oldest 8 = current tile). __syncthreads' forced vmcnt(0) drain was the
//   ~20% structural stall (m97-model); counted-vmcnt is T4 (m218/m248).
// BM==64: VGPR staging + padded LDS (latency-bound shapes; GL re-tested r6 —
//   regressed; 64x64 tile re-tested r8 — 104us disaster).
// XSWZ: 1D-chunked XCD swizzle (t6 split-K; neutral-by-symmetry for t1/t5).
// EPI: 0 bias->bf16 ; 1 bias+gelu->bf16 ; 2 bias+f32resid->bf16 ; 3 bias+bf16resid->f32
//      4 split-K=2 raw fp32 partial (z=0 -> Cout, z=1 -> resid-as-output; no bias)
// ---------------------------------------------------------------------------
template <int EPI, int BM, bool XSWZ>
__global__ __launch_bounds__(256) void gemm_kernel(const bf16* __restrict__ A,
                                                   const bf16* __restrict__ Bt,
                                                   const float* __restrict__ bias,
                                                   const void* __restrict__ resid,
                                                   void* __restrict__ Cout,
                                                   int M, int N, int K) {
    constexpr int IF = 4;
    constexpr int JF = (BM == 128) ? 4 : 2;
    constexpr bool GL = (BM == 128);
    constexpr int ST = GL ? 64 : 72;
    constexpr int NB = GL ? 2 : 1;
    __shared__ __align__(16) bf16 As[NB][BM * ST];
    __shared__ __align__(16) bf16 Bs[NB][128 * ST];
    const int tid  = threadIdx.x;
    const int wave = tid >> 6, lane = tid & 63;
    const int quad = lane >> 4, l16 = lane & 15;
    const int wm = GL ? (wave >> 1) * 64 : 0;
    const int wn = GL ? (wave & 1) * 64 : wave * 32;

    int bx = blockIdx.x, by = blockIdx.y, bz = blockIdx.z;
    if constexpr (XSWZ) {
        const int gx = gridDim.x, gy = gridDim.y;
        const int nwg = gx * gy * gridDim.z;     // must be % 8 == 0
        const int f = bx + gx * (by + gy * bz);
        const int s = (f & 7) * (nwg >> 3) + (f >> 3);
        bx = s % gx; int rem = s / gx; by = rem % gy; bz = rem / gy;
    }
    const int bm = by * BM, bn = bx * 128;

    int kz0 = 0, kz1 = K;
    if constexpr (EPI == 4) {
        kz0 = bz * (K >> 1);
        kz1 = kz0 + (K >> 1);
    }

    // swizzled per-lane global source for GLLDS (row base ≡ 0 mod 8 so
    // row&7 == r8; physical chunk (lane&7) at row r holds logical chunk ^r8)
    const int r8 = lane >> 3, sc = lane & 7;
    const bf16* ag = A  + (size_t)(bm + wave * 8 + r8) * K + ((sc ^ r8) << 3);
    const bf16* bg = Bt + (size_t)(bn + wave * 8 + r8) * K + ((sc ^ r8) << 3);

    f32x4 acc[IF][JF];
#pragma unroll
    for (int i = 0; i < IF; ++i)
#pragma unroll
        for (int j = 0; j < JF; ++j) acc[i][j] = (f32x4){0.f, 0.f, 0.f, 0.f};

    if constexpr (GL) {
        auto stage = [&](int buf, int kt) {   // 8 GLLDS per wave
#pragma unroll
            for (int i = 0; i < 4; ++i) {
                GLLDS16(ag + (size_t)(i * 32) * K + kt, &As[buf][(wave * 8 + i * 32) * 64]);
                GLLDS16(bg + (size_t)(i * 32) * K + kt, &Bs[buf][(wave * 8 + i * 32) * 64]);
            }
        };
        auto compute = [&](int buf) {
#pragma unroll
            for (int ks = 0; ks < 2; ++ks) {
                bf16x8 af[IF], bfr[JF];
                const int swr = l16 & 7;
#pragma unroll
                for (int i = 0; i < IF; ++i)
                    af[i] = *(const bf16x8*)(&As[buf][(wm + i * 16 + l16) * 64 +
                                                      (((ks * 4 + quad) ^ swr) << 3)]);
#pragma unroll
                for (int j = 0; j < JF; ++j)
                    bfr[j] = *(const bf16x8*)(&Bs[buf][(wn + j * 16 + l16) * 64 +
                                                       (((ks * 4 + quad) ^ swr) << 3)]);
#pragma unroll
                for (int i = 0; i < IF; ++i)
#pragma unroll
                    for (int j = 0; j < JF; ++j)
                        acc[i][j] = __builtin_amdgcn_mfma_f32_16x16x32_bf16(af[i], bfr[j], acc[i][j], 0, 0, 0);
            }
        };
        // T4 pipeline: 2 tiles in flight, vmcnt(8) retires oldest tile only;
        // prefetch survives the barrier. Epilogue alone drains to 0.
        stage(0, kz0);
        stage(1, kz0 + 64);                    // K >= 128 for all GL launches
        int cur = 0;
        for (int kt = kz0; kt < kz1 - 64; kt += 64) {
            asm volatile("s_waitcnt vmcnt(8)" ::: "memory");   // cur tile landed
            __builtin_amdgcn_s_barrier();                      // ..for all waves
            compute(cur);
            asm volatile("s_waitcnt lgkmcnt(0)" ::: "memory"); // reads of cur done
            __builtin_amdgcn_s_barrier();                      // ..for all waves
            if (kt + 128 < kz1) stage(cur, kt + 128);          // reuse cur buf
            cur ^= 1;
        }
        asm volatile("s_waitcnt vmcnt(0)" ::: "memory");       // last tile landed
        __builtin_amdgcn_s_barrier();
        compute(cur);
    } else {
        for (int kt = kz0; kt < kz1; kt += 64) {
            __syncthreads();
#pragma unroll
            for (int i = 0; i < BM * 8 / 256; ++i) {
                int c0 = tid + i * 256;
                int r = c0 >> 3, kc = (c0 & 7) << 3;
                *(uint4*)(&As[0][r * ST + kc]) = *(const uint4*)(A + (size_t)(bm + r) * K + kt + kc);
            }
#pragma unroll
            for (int i = 0; i < 4; ++i) {
                int c0 = tid + i * 256;
                int r = c0 >> 3, kc = (c0 & 7) << 3;
                *(uint4*)(&Bs[0][r * ST + kc]) = *(const uint4*)(Bt + (size_t)(bn + r) * K + kt + kc);
            }
            __syncthreads();
#pragma unroll
            for (int ks = 0; ks < 2; ++ks) {
                bf16x8 af[IF], bfr[JF];
#pragma unroll
                for (int i = 0; i < IF; ++i)
                    af[i] = *(const bf16x8*)(&As[0][(wm + i * 16 + l16) * ST + ks * 32 + quad * 8]);
#pragma unroll
                for (int j = 0; j < JF; ++j)
                    bfr[j] = *(const bf16x8*)(&Bs[0][(wn + j * 16 + l16) * ST + ks * 32 + quad * 8]);
#pragma unroll
                for (int i = 0; i < IF; ++i)
#pragma unroll
                    for (int j = 0; j < JF; ++j)
                        acc[i][j] = __builtin_amdgcn_mfma_f32_16x16x32_bf16(af[i], bfr[j], acc[i][j], 0, 0, 0);
            }
        }
    }
    // epilogue: C/D layout col=lane&15, row=quad*4+reg
    float* skdst = nullptr;
    if constexpr (EPI == 4)
        skdst = bz ? (float*)const_cast<void*>(resid) : (float*)Cout;
#pragma unroll
    for (int i = 0; i < IF; ++i) {
#pragma unroll
        for (int j = 0; j < JF; ++j) {
#pragma unroll
            for (int r = 0; r < 4; ++r) {
                const int row = bm + wm + i * 16 + quad * 4 + r;
                const int col = bn + wn + j * 16 + l16;
                float v = acc[i][j][r];
                if constexpr (EPI != 4) v += bias[col];
                if constexpr (EPI == 1)
                    v = gelu_f(v);
                if constexpr (EPI == 2) {
                    v += ((const float*)resid)[(size_t)row * N + col];
                    ((bf16*)Cout)[(size_t)row * N + col] = __float2bfloat16(v);
                } else if constexpr (EPI == 3) {
                    v += bf2f(((const unsigned short*)resid)[(size_t)row * N + col]);
                    ((float*)Cout)[(size_t)row * N + col] = v;
                } else if constexpr (EPI == 4) {
                    skdst[(size_t)row * N + col] = v;
                } else {
                    ((bf16*)Cout)[(size_t)row * N + col] = __float2bfloat16(v);
                }
            }
        }
    }
}

// ---------------------------------------------------------------------------
// Split-K merge for fc2: out = p0 + p1 + bias + bf16resid (fp32 out, in-place
// over p0).
// ---------------------------------------------------------------------------
__global__ __launch_bounds__(256) void merge_fc2(const float* __restrict__ p0,
                                                 const float* __restrict__ p1,
                                                 const float* __restrict__ bias,
                                                 const bf16* __restrict__ resid,
                                                 float* __restrict__ outp) {
    const int idx = blockIdx.x * 256 + threadIdx.x;
    const int row = idx >> 8, col = (idx & 255) * 4;
    const size_t off = (size_t)row * 1024 + col;
    float4 a = *(const float4*)(p0 + off);
    float4 b = *(const float4*)(p1 + off);
    float4 bs = *(const float4*)(bias + col);
    ushort4 r = *(const ushort4*)((const unsigned short*)resid + off);
    float4 o;
    o.x = a.x + b.x + bs.x + bf2f(r.x);
    o.y = a.y + b.y + bs.y + bf2f(r.y);
    o.z = a.z + b.z + bs.z + bf2f(r.z);
    o.w = a.w + b.w + bs.w + bf2f(r.w);
    *(float4*)(outp + off) = o;
}

// ---------------------------------------------------------------------------
// Flash attention, split-KV x2, NO running max (scores bounded by
// construction). P = exp(s) directly; row-sum l via ones-MFMA.
// Ks/Vs XOR-swizzled; single-buffered (r4: dbuf regressed — TLP covers
// latency); NO setprio (r6: regressed — 4-wave lockstep = m190 regime).
// XCD-chunked grid swizzle (r7: FETCH 71.7 -> 16.4 MB, K/V L2-resident).
// Two-set structure (r10 per-set Ps: +3.7us — grid caps residency, not LDS;
// r11 QBLK=64: +10us — doubles chip-wide staging work). 62us floor is
// per-block staging+exp serial cost; next lever is in-register softmax
// (swapped QK^T, T12) — structural rewrite, future session.
// Writes UNNORMALIZED partial O (bf16) + per-row l (f32).
// ---------------------------------------------------------------------------
__global__ __launch_bounds__(256) void attn_kernel(const bf16* __restrict__ qkv,
                                                   const bf16* __restrict__ vtg,
                                                   bf16* __restrict__ Opart,
                                                   float* __restrict__ Lp) {
    __shared__ __align__(16) bf16 Ks[64 * 64];      // [s][c], swizzled
    __shared__ __align__(16) bf16 Vs[64 * 64];      // [c][s_local], swizzled
    __shared__ __align__(16) bf16 Ps[4][2][16][72]; // per-wave, per-set P tiles
    const int tid  = threadIdx.x;
    const int wave = tid >> 6, lane = tid & 63;
    const int quad = lane >> 4, l16 = lane & 15;
    // XCD-chunked remap of (qt, h, z): nwg = 16*16*4 = 1024, 128 per XCD
    const int f = blockIdx.x + 16 * blockIdx.y + 256 * blockIdx.z;
    const int sid = (f & 7) * 128 + (f >> 3);
    const int qt = sid & 15, h = (sid >> 4) & 15;
    const int zz = sid >> 8;
    const int b = zz >> 1, seg = zz & 1;
    const size_t tok0 = (size_t)b * 2048;
    const int qbase = qt * 128 + wave * 32;

    bf16x8 qf[2][2];
#pragma unroll
    for (int set = 0; set < 2; ++set) {
        const bf16* qp = qkv + (tok0 + qbase + set * 16 + l16) * 3072 + h * 192 + quad * 8;
        qf[set][0] = *(const bf16x8*)(qp);
        qf[set][1] = *(const bf16x8*)(qp + 32);
    }

    // lane l writes LDS row (l>>3), physical chunk (l&7); physical chunk p at
    // row r holds logical chunk p^(r&7)  ->  source loads logical (l&7)^(l>>3)
    const int swc = ((tid & 7) ^ ((tid >> 3) & 7)) * 8;
    const bf16* kg = qkv + (tok0 + (tid >> 3)) * 3072 + h * 192 + 64 + swc;
    const bf16* vg = vtg + ((size_t)(b * 16 + h) * 64 + (tid >> 3)) * 2048 + swc;

    // ones B-frag for row-sum MFMA
    const short oneb = 0x3f80;
    const bf16x8 ones = {oneb, oneb, oneb, oneb, oneb, oneb, oneb, oneb};

    f32x4 o[2][4], l_acc[2];
#pragma unroll
    for (int set = 0; set < 2; ++set) {
        l_acc[set] = (f32x4){0.f, 0.f, 0.f, 0.f};
#pragma unroll
        for (int j = 0; j < 4; ++j) o[set][j] = (f32x4){0.f, 0.f, 0.f, 0.f};
    }

    const int kt0 = seg * 1024;
    for (int kt = kt0; kt < kt0 + 1024; kt += 64) {
        __syncthreads();
        GLLDS16(kg + (size_t)kt * 3072,        &Ks[(wave * 64) * 8]);
        GLLDS16(kg + (size_t)(kt + 32) * 3072, &Ks[(wave * 64 + 256) * 8]);
        GLLDS16(vg + kt,                       &Vs[(wave * 64) * 8]);
        GLLDS16(vg + kt + 32 * 2048,           &Vs[(wave * 64 + 256) * 8]);
        __syncthreads();

        // S = Q K^T ; P = exp(S/8) straight into LDS (C-layout -> A-layout)
#pragma unroll
        for (int j = 0; j < 4; ++j) {
            const int rk = j * 16 + l16;
            const int sw = l16 & 7;             // rk&7 == l16&7 (j*16 ≡ 0 mod 8)
            bf16x8 kb0 = *(const bf16x8*)(&Ks[rk * 64 + ((quad ^ sw) * 8)]);
            bf16x8 kb1 = *(const bf16x8*)(&Ks[rk * 64 + (((quad + 4) ^ sw) * 8)]);
#pragma unroll
            for (int set = 0; set < 2; ++set) {
                f32x4 s4 = (f32x4){0.f, 0.f, 0.f, 0.f};
                s4 = __builtin_amdgcn_mfma_f32_16x16x32_bf16(qf[set][0], kb0, s4, 0, 0, 0);
                s4 = __builtin_amdgcn_mfma_f32_16x16x32_bf16(qf[set][1], kb1, s4, 0, 0, 0);
#pragma unroll
                for (int r = 0; r < 4; ++r)
                    Ps[wave][set][quad * 4 + r][j * 16 + l16] =
                        __float2bfloat16(__expf(s4[r] * 0.125f));
            }
        }
        // O += P V ; l += P 1   (per-wave Ps: same-wave write->read)
#pragma unroll
        for (int kk = 0; kk < 2; ++kk) {
            bf16x8 pf0 = *(const bf16x8*)(&Ps[wave][0][l16][kk * 32 + quad * 8]);
            bf16x8 pf1 = *(const bf16x8*)(&Ps[wave][1][l16][kk * 32 + quad * 8]);
            l_acc[0] = __builtin_amdgcn_mfma_f32_16x16x32_bf16(pf0, ones, l_acc[0], 0, 0, 0);
            l_acc[1] = __builtin_amdgcn_mfma_f32_16x16x32_bf16(pf1, ones, l_acc[1], 0, 0, 0);
#pragma unroll
            for (int j = 0; j < 4; ++j) {
                const int rv = j * 16 + l16;
                bf16x8 vf = *(const bf16x8*)(&Vs[rv * 64 + (((kk * 4 + quad) ^ (l16 & 7)) * 8)]);
                o[0][j] = __builtin_amdgcn_mfma_f32_16x16x32_bf16(pf0, vf, o[0][j], 0, 0, 0);
                o[1][j] = __builtin_amdgcn_mfma_f32_16x16x32_bf16(pf1, vf, o[1][j], 0, 0, 0);
            }
        }
    }
    // write unnormalized partials + l
    const size_t segoff = (size_t)seg * 4096;
#pragma unroll
    for (int set = 0; set < 2; ++set)
#pragma unroll
        for (int j = 0; j < 4; ++j)
#pragma unroll
            for (int r = 0; r < 4; ++r) {
                int row = qbase + set * 16 + quad * 4 + r;
                Opart[(segoff + tok0 + row) * 1024 + h * 64 + j * 16 + l16] =
                    __float2bfloat16(o[set][j][r]);
            }
    if (l16 == 0) {
#pragma unroll
        for (int set = 0; set < 2; ++set)
#pragma unroll
            for (int r = 0; r < 4; ++r) {
                int row = qbase + set * 16 + quad * 4 + r;
                Lp[(segoff + tok0 + row) * 16 + h] = l_acc[set][r];
            }
    }
}

// ---------------------------------------------------------------------------
// Merge two KV-segments: out = (O0 + O1) / (l0 + l1).
// ---------------------------------------------------------------------------
__global__ __launch_bounds__(256) void merge_kernel(const bf16* __restrict__ Opart,
                                                    const float* __restrict__ Lp,
                                                    bf16* __restrict__ outp) {
    const int idx = blockIdx.x * 256 + threadIdx.x;
    const int c4 = idx & 15, h = (idx >> 4) & 15, gt = idx >> 8;
    const size_t li0 = (size_t)gt * 16 + h, li1 = li0 + 4096 * 16;
    float inv = 1.0f / (Lp[li0] + Lp[li1]);
    const size_t off = (size_t)gt * 1024 + h * 64 + c4 * 4;
    ushort4 a = *(const ushort4*)((const unsigned short*)Opart + off);
    ushort4 bb = *(const ushort4*)((const unsigned short*)Opart + off + (size_t)4096 * 1024);
    float va[4] = {bf2f(a.x), bf2f(a.y), bf2f(a.z), bf2f(a.w)};
    float vb[4] = {bf2f(bb.x), bf2f(bb.y), bf2f(bb.z), bf2f(bb.w)};
    unsigned short res[4];
#pragma unroll
    for (int e = 0; e < 4; ++e) {
        bf16 o = __float2bfloat16((va[e] + vb[e]) * inv);
        res[e] = *(unsigned short*)&o;
    }
    *(ushort4*)((unsigned short*)outp + off) = make_ushort4(res[0], res[1], res[2], res[3]);
}

// ---------------------------------------------------------------------------
// Workspace map (64 MB, lifetime-aliased; launch order t0..t6):
//  [ 0, 8)  wfcT      t0 -> t5 ; fc2 split-K partial1 [0,16) t6 -> t6.5
//  [ 8,16)  ln1 out   t0 -> t1 ; wprojT [8,10) t1.6->t3 ; Lp [10,10.5) t2->t2.5 ; ln2 t4->t5
//  [16,22)  wqkvT     t0 -> t1
//  [16,24)  vtg       t1.5 -> t2 ; attn-out t2.5 -> t3 ; fcact(lo) t5->t6
//  [24,48)  qkvb      t1 -> t2 ; fcact(hi) t5 -> t6
//  [48,64)  Opart     t2 -> t2.5 ; wfc2T [48,56) t2.6->t6 ; x1 bf16 [56,64) t3->t6.5
// ---------------------------------------------------------------------------
extern "C" void kernel_launch(void* const* d_in, const int* in_sizes, int n_in,
                              void* d_out, int out_size, void* d_ws, size_t ws_size,
                              hipStream_t stream) {
    const float* x      = (const float*)d_in[0];
    const float* ln1_g  = (const float*)d_in[1];
    const float* ln1_b  = (const float*)d_in[2];
    const float* qkv_w  = (const float*)d_in[3];
    const float* qkv_b  = (const float*)d_in[4];
    const float* proj_w = (const float*)d_in[5];
    const float* proj_b = (const float*)d_in[6];
    const float* ln2_g  = (const float*)d_in[7];
    const float* ln2_b  = (const float*)d_in[8];
    const float* fc_w   = (const float*)d_in[9];
    const float* fc_b   = (const float*)d_in[10];
    const float* fc2_w  = (const float*)d_in[11];
    const float* fc2_b  = (const float*)d_in[12];
    float* outp = (float*)d_out;

    char* ws = (char*)d_ws;
    const size_t MB = 1024 * 1024;
    bf16*  wfcT   = (bf16*)(ws + 0 * MB);
    float* part1  = (float*)(ws + 0 * MB);   // fc2 split-K partial (16 MB, dead wfcT+lnbuf)
    bf16*  lnbuf  = (bf16*)(ws + 8 * MB);    // ln1 / ln2 slab
    bf16*  wprojT = (bf16*)(ws + 8 * MB);
    float* Lp     = (float*)(ws + 10 * MB);
    bf16*  wqkvT  = (bf16*)(ws + 16 * MB);
    bf16*  vtg    = (bf16*)(ws + 16 * MB);
    bf16*  attnout= (bf16*)(ws + 16 * MB);
    bf16*  fcact  = (bf16*)(ws + 16 * MB);   // [16,48)
    bf16*  qkvb   = (bf16*)(ws + 24 * MB);
    bf16*  Opart  = (bf16*)(ws + 48 * MB);
    bf16*  wfc2T  = (bf16*)(ws + 48 * MB);
    bf16*  x1     = (bf16*)(ws + 56 * MB);

    // t0: qkv+fc transposes (ONE dispatch) + ln1
    transpose2_f2b<<<dim3(96 + 128, 32), 256, 0, stream>>>(qkv_w, wqkvT, 3072, 96,
                                                           fc_w,  wfcT,  4096, 1024);
    ln_kernel<float><<<4096, 256, 0, stream>>>(x, ln1_g, ln1_b, lnbuf);
    // t1: qkv = ln1 @ qkv_w + b
    gemm_kernel<0, 128, false><<<dim3(24, 32), 256, 0, stream>>>(lnbuf, wqkvT, qkv_b, nullptr, qkvb, 4096, 3072, 1024);
    // t1.5: V pre-transpose (overwrites wqkvT region — dead)
    vtrans_kernel<<<dim3(64, 2, 32), 256, 0, stream>>>(qkvb, vtg);
    // t1.6: proj transpose (into dead ln1 region)
    transpose_f2b<<<dim3(32, 32), 256, 0, stream>>>(proj_w, wprojT, 1024, 1024);
    // t2: attention split-KV x2 (1024 blocks, XCD-chunked)
    attn_kernel<<<dim3(16, 16, 4), 256, 0, stream>>>(qkvb, vtg, Opart, Lp);
    // t2.5: merge segments -> attn-out (overwrites vtg — dead)
    merge_kernel<<<4096, 256, 0, stream>>>(Opart, Lp, attnout);
    // t2.6: fc2 transpose (into dead Opart region)
    transpose_f2b<<<dim3(32, 128), 256, 0, stream>>>(fc2_w, wfc2T, 4096, 1024);
    // t3: x1 = x + attn @ proj_w + b   (BM=64: 512 blocks, XCD-swizzled)
    gemm_kernel<2, 64, true><<<dim3(8, 64), 256, 0, stream>>>(attnout, wprojT, proj_b, x, x1, 4096, 1024, 1024);
    // t4: ln2(x1)
    ln_kernel<bf16><<<4096, 256, 0, stream>>>(x1, ln2_g, ln2_b, lnbuf);
    // t5: fcact = gelu(ln2 @ fc_w + b)
    gemm_kernel<1, 128, false><<<dim3(32, 32), 256, 0, stream>>>(lnbuf, wfcT, fc_b, nullptr, fcact, 4096, 4096, 1024);
    // t6: split-K=2 fc2 partials: z=0 -> outp, z=1 -> part1  (1024 blocks, XCD-swizzled)
    gemm_kernel<4, 64, true><<<dim3(8, 64, 2), 256, 0, stream>>>(fcact, wfc2T, nullptr, part1, outp, 4096, 1024, 4096);
    // t6.5: out = p0 + p1 + bias + x1
    merge_fc2<<<4096, 256, 0, stream>>>(outp, part1, fc2_b, x1, outp);
}

// Round 14
// 368.528 us; speedup vs baseline: 1.0101x; 1.0101x over previous
//
#include <hip/hip_runtime.h>
#include <hip/hip_bf16.h>
#include <type_traits>
#include <cstdint>

using bf16 = __hip_bfloat16;
typedef __attribute__((ext_vector_type(8))) short bf16x8;   // MFMA A/B frag (4 VGPRs)
typedef __attribute__((ext_vector_type(4))) float f32x4;    // MFMA C/D frag

__device__ __forceinline__ float bf2f(unsigned short u) {
    union { unsigned int i; float f; } c; c.i = ((unsigned int)u) << 16; return c.f;
}

// Branchless exact-GELU: A&S 7.1.26 erf (|err|<1.5e-7, far below bf16 rounding)
__device__ __forceinline__ float gelu_f(float v) {
    float x  = v * 0.70710678118654752f;
    float ax = fabsf(x);
    float t  = __builtin_amdgcn_rcpf(1.0f + 0.3275911f * ax);
    float poly = ((((1.061405429f * t - 1.453152027f) * t + 1.421413741f) * t
                   - 0.284496736f) * t + 0.254829592f) * t;
    float erfv = 1.0f - poly * __expf(-ax * ax);
    erfv = copysignf(erfv, x);
    return 0.5f * v * (1.0f + erfv);
}

// async global->LDS, 16 B per lane; lds dest must be wave-uniform base (+lane*16)
#define GLLDS16(gp, lp)                                                          \
    __builtin_amdgcn_global_load_lds(                                            \
        (const __attribute__((address_space(1))) void*)(gp),                     \
        (__attribute__((address_space(3))) void*)(lp), 16, 0, 0)

// ---------------------------------------------------------------------------
// Fused convert+transpose: w[K][N] fp32 -> wt[N][K] bf16, 32x32 LDS tiles.
// ---------------------------------------------------------------------------
__global__ __launch_bounds__(256) void transpose_f2b(const float* __restrict__ w,
                                                     bf16* __restrict__ wt,
                                                     int K, int N) {
    __shared__ bf16 t[32][33];
    const int tid = threadIdx.x;
    const int n0 = blockIdx.x * 32, k0 = blockIdx.y * 32;
#pragma unroll
    for (int i = 0; i < 4; ++i) {
        int idx = tid + i * 256;
        int r = idx >> 5, c = idx & 31;
        t[r][c] = __float2bfloat16(w[(size_t)(k0 + r) * N + n0 + c]);
    }
    __syncthreads();
#pragma unroll
    for (int i = 0; i < 4; ++i) {
        int idx = tid + i * 256;
        int r = idx >> 5, c = idx & 31;
        wt[(size_t)(n0 + r) * K + k0 + c] = t[c][r];
    }
}

// ---------------------------------------------------------------------------
// Dual transpose: two weight matrices (shared K=1024) in ONE dispatch.
// ---------------------------------------------------------------------------
__global__ __launch_bounds__(256) void transpose2_f2b(const float* __restrict__ w0,
                                                      bf16* __restrict__ wt0,
                                                      int N0, int nb0,
                                                      const float* __restrict__ w1,
                                                      bf16* __restrict__ wt1,
                                                      int N1, int K) {
    __shared__ bf16 t[32][33];
    const int tid = threadIdx.x;
    int bx = blockIdx.x;
    const float* w; bf16* wt; int N;
    if (bx < nb0) { w = w0; wt = wt0; N = N0; }
    else          { w = w1; wt = wt1; N = N1; bx -= nb0; }
    const int n0 = bx * 32, k0 = blockIdx.y * 32;
#pragma unroll
    for (int i = 0; i < 4; ++i) {
        int idx = tid + i * 256;
        int r = idx >> 5, c = idx & 31;
        t[r][c] = __float2bfloat16(w[(size_t)(k0 + r) * N + n0 + c]);
    }
    __syncthreads();
#pragma unroll
    for (int i = 0; i < 4; ++i) {
        int idx = tid + i * 256;
        int r = idx >> 5, c = idx & 31;
        wt[(size_t)(n0 + r) * K + k0 + c] = t[c][r];
    }
}

// ---------------------------------------------------------------------------
// V pre-transpose: qkv[token][h*192+128+c] -> vtg[(b*16+h)][c][s]  (bf16)
// ---------------------------------------------------------------------------
__global__ __launch_bounds__(256) void vtrans_kernel(const bf16* __restrict__ qkv,
                                                     bf16* __restrict__ vtg) {
    __shared__ bf16 t[32][33];
    const int tid = threadIdx.x;
    const int s0 = blockIdx.x * 32, c0 = blockIdx.y * 32;
    const int bh = blockIdx.z, b = bh >> 4, h = bh & 15;
#pragma unroll
    for (int i = 0; i < 4; ++i) {
        int idx = tid + i * 256;
        int r = idx >> 5, c = idx & 31;
        t[r][c] = qkv[(size_t)(b * 2048 + s0 + r) * 3072 + h * 192 + 128 + c0 + c];
    }
    __syncthreads();
#pragma unroll
    for (int i = 0; i < 4; ++i) {
        int idx = tid + i * 256;
        int r = idx >> 5, c = idx & 31;
        vtg[((size_t)bh * 64 + c0 + r) * 2048 + s0 + c] = t[c][r];
    }
}

// ---------------------------------------------------------------------------
// LayerNorm over W=1024: one block per row, 256 threads x 4 elems.
// ---------------------------------------------------------------------------
template <typename InT>
__global__ __launch_bounds__(256) void ln_kernel(const InT* __restrict__ x,
                                                 const float* __restrict__ g,
                                                 const float* __restrict__ bta,
                                                 bf16* __restrict__ y) {
    const int row = blockIdx.x, tid = threadIdx.x;
    const size_t base = (size_t)row * 1024 + tid * 4;
    float v[4];
    if constexpr (std::is_same_v<InT, float>) {
        float4 f = *(const float4*)(x + base);
        v[0] = f.x; v[1] = f.y; v[2] = f.z; v[3] = f.w;
    } else {
        ushort4 u = *(const ushort4*)((const unsigned short*)x + base);
        v[0] = bf2f(u.x); v[1] = bf2f(u.y); v[2] = bf2f(u.z); v[3] = bf2f(u.w);
    }
    float s = v[0] + v[1] + v[2] + v[3];
    float sq = v[0]*v[0] + v[1]*v[1] + v[2]*v[2] + v[3]*v[3];
#pragma unroll
    for (int off = 32; off > 0; off >>= 1) {
        s  += __shfl_down(s, off);
        sq += __shfl_down(sq, off);
    }
    __shared__ float red[8];
    const int wave = tid >> 6, lane = tid & 63;
    if (lane == 0) { red[wave] = s; red[4 + wave] = sq; }
    __syncthreads();
    s  = red[0] + red[1] + red[2] + red[3];
    sq = red[4] + red[5] + red[6] + red[7];
    const float mu   = s * (1.0f / 1024.0f);
    const float var  = sq * (1.0f / 1024.0f) - mu * mu;
    const float rstd = rsqrtf(var + 1e-5f);
#pragma unroll
    for (int e = 0; e < 4; ++e) {
        int col = tid * 4 + e;
        float yy = (v[e] - mu) * rstd * g[col] + bta[col];
        y[base + e] = __float2bfloat16(yy);
    }
}

// ---------------------------------------------------------------------------
// GEMM: C[M,N] = A[M,K] @ B[K,N] (+bias fp32, epilogue). A,Bt bf16; Bt=[N][K].
// BM x 128 tile, BK=64, 4 waves, 16x16x32 bf16 MFMA.
// BM==128: GLLDS16 staging + XOR-16B-chunk swizzle + 2-phase dbuf prefetch.
//   (T4 counted-vmcnt re-tested r13 — null at 2-phase, regime gate: needs
//   the 8-phase fine interleave to pay. Keep __syncthreads dbuf.)
// BM==64: VGPR staging + padded LDS (latency-bound shapes; GL re-tested r6 —
//   regressed; 64x64 tile re-tested r8 — 104us disaster).
// XSWZ: 1D-chunked XCD swizzle (t6 split-K; neutral-by-symmetry for t1/t5).
// EPI: 0 bias->bf16 ; 1 bias+gelu->bf16 ; 2 bias+f32resid->bf16 ; 3 bias+bf16resid->f32
//      4 split-K=2 raw fp32 partial (z=0 -> Cout, z=1 -> resid-as-output; no bias)
// ---------------------------------------------------------------------------
template <int EPI, int BM, bool XSWZ>
__global__ __launch_bounds__(256) void gemm_kernel(const bf16* __restrict__ A,
                                                   const bf16* __restrict__ Bt,
                                                   const float* __restrict__ bias,
                                                   const void* __restrict__ resid,
                                                   void* __restrict__ Cout,
                                                   int M, int N, int K) {
    constexpr int IF = 4;
    constexpr int JF = (BM == 128) ? 4 : 2;
    constexpr bool GL = (BM == 128);
    constexpr int ST = GL ? 64 : 72;
    constexpr int NB = GL ? 2 : 1;
    __shared__ __align__(16) bf16 As[NB][BM * ST];
    __shared__ __align__(16) bf16 Bs[NB][128 * ST];
    const int tid  = threadIdx.x;
    const int wave = tid >> 6, lane = tid & 63;
    const int quad = lane >> 4, l16 = lane & 15;
    const int wm = GL ? (wave >> 1) * 64 : 0;
    const int wn = GL ? (wave & 1) * 64 : wave * 32;

    int bx = blockIdx.x, by = blockIdx.y, bz = blockIdx.z;
    if constexpr (XSWZ) {
        const int gx = gridDim.x, gy = gridDim.y;
        const int nwg = gx * gy * gridDim.z;     // must be % 8 == 0
        const int f = bx + gx * (by + gy * bz);
        const int s = (f & 7) * (nwg >> 3) + (f >> 3);
        bx = s % gx; int rem = s / gx; by = rem % gy; bz = rem / gy;
    }
    const int bm = by * BM, bn = bx * 128;

    int kz0 = 0, kz1 = K;
    if constexpr (EPI == 4) {
        kz0 = bz * (K >> 1);
        kz1 = kz0 + (K >> 1);
    }

    // swizzled per-lane global source for GLLDS (row base ≡ 0 mod 8 so
    // row&7 == r8; physical chunk (lane&7) at row r holds logical chunk ^r8)
    const int r8 = lane >> 3, sc = lane & 7;
    const bf16* ag = A  + (size_t)(bm + wave * 8 + r8) * K + ((sc ^ r8) << 3);
    const bf16* bg = Bt + (size_t)(bn + wave * 8 + r8) * K + ((sc ^ r8) << 3);

    f32x4 acc[IF][JF];
#pragma unroll
    for (int i = 0; i < IF; ++i)
#pragma unroll
        for (int j = 0; j < JF; ++j) acc[i][j] = (f32x4){0.f, 0.f, 0.f, 0.f};

    if constexpr (GL) {
        auto stage = [&](int buf, int kt) {
#pragma unroll
            for (int i = 0; i < 4; ++i) {
                GLLDS16(ag + (size_t)(i * 32) * K + kt, &As[buf][(wave * 8 + i * 32) * 64]);
                GLLDS16(bg + (size_t)(i * 32) * K + kt, &Bs[buf][(wave * 8 + i * 32) * 64]);
            }
        };
        auto compute = [&](int buf) {
#pragma unroll
            for (int ks = 0; ks < 2; ++ks) {
                bf16x8 af[IF], bfr[JF];
                const int swr = l16 & 7;
#pragma unroll
                for (int i = 0; i < IF; ++i)
                    af[i] = *(const bf16x8*)(&As[buf][(wm + i * 16 + l16) * 64 +
                                                      (((ks * 4 + quad) ^ swr) << 3)]);
#pragma unroll
                for (int j = 0; j < JF; ++j)
                    bfr[j] = *(const bf16x8*)(&Bs[buf][(wn + j * 16 + l16) * 64 +
                                                       (((ks * 4 + quad) ^ swr) << 3)]);
#pragma unroll
                for (int i = 0; i < IF; ++i)
#pragma unroll
                    for (int j = 0; j < JF; ++j)
                        acc[i][j] = __builtin_amdgcn_mfma_f32_16x16x32_bf16(af[i], bfr[j], acc[i][j], 0, 0, 0);
            }
        };
        stage(0, kz0);
        __syncthreads();               // prefetch 0 landed
        int cur = 0;
        for (int kt = kz0; kt < kz1; kt += 64) {
            if (kt + 64 < kz1) stage(cur ^ 1, kt + 64);   // issue-early
            compute(cur);
            __syncthreads();           // publishes prefetch + retires reads
            cur ^= 1;
        }
    } else {
        for (int kt = kz0; kt < kz1; kt += 64) {
            __syncthreads();
#pragma unroll
            for (int i = 0; i < BM * 8 / 256; ++i) {
                int c0 = tid + i * 256;
                int r = c0 >> 3, kc = (c0 & 7) << 3;
                *(uint4*)(&As[0][r * ST + kc]) = *(const uint4*)(A + (size_t)(bm + r) * K + kt + kc);
            }
#pragma unroll
            for (int i = 0; i < 4; ++i) {
                int c0 = tid + i * 256;
                int r = c0 >> 3, kc = (c0 & 7) << 3;
                *(uint4*)(&Bs[0][r * ST + kc]) = *(const uint4*)(Bt + (size_t)(bn + r) * K + kt + kc);
            }
            __syncthreads();
#pragma unroll
            for (int ks = 0; ks < 2; ++ks) {
                bf16x8 af[IF], bfr[JF];
#pragma unroll
                for (int i = 0; i < IF; ++i)
                    af[i] = *(const bf16x8*)(&As[0][(wm + i * 16 + l16) * ST + ks * 32 + quad * 8]);
#pragma unroll
                for (int j = 0; j < JF; ++j)
                    bfr[j] = *(const bf16x8*)(&Bs[0][(wn + j * 16 + l16) * ST + ks * 32 + quad * 8]);
#pragma unroll
                for (int i = 0; i < IF; ++i)
#pragma unroll
                    for (int j = 0; j < JF; ++j)
                        acc[i][j] = __builtin_amdgcn_mfma_f32_16x16x32_bf16(af[i], bfr[j], acc[i][j], 0, 0, 0);
            }
        }
    }
    // epilogue: C/D layout col=lane&15, row=quad*4+reg
    float* skdst = nullptr;
    if constexpr (EPI == 4)
        skdst = bz ? (float*)const_cast<void*>(resid) : (float*)Cout;
#pragma unroll
    for (int i = 0; i < IF; ++i) {
#pragma unroll
        for (int j = 0; j < JF; ++j) {
#pragma unroll
            for (int r = 0; r < 4; ++r) {
                const int row = bm + wm + i * 16 + quad * 4 + r;
                const int col = bn + wn + j * 16 + l16;
                float v = acc[i][j][r];
                if constexpr (EPI != 4) v += bias[col];
                if constexpr (EPI == 1)
                    v = gelu_f(v);
                if constexpr (EPI == 2) {
                    v += ((const float*)resid)[(size_t)row * N + col];
                    ((bf16*)Cout)[(size_t)row * N + col] = __float2bfloat16(v);
                } else if constexpr (EPI == 3) {
                    v += bf2f(((const unsigned short*)resid)[(size_t)row * N + col]);
                    ((float*)Cout)[(size_t)row * N + col] = v;
                } else if constexpr (EPI == 4) {
                    skdst[(size_t)row * N + col] = v;
                } else {
                    ((bf16*)Cout)[(size_t)row * N + col] = __float2bfloat16(v);
                }
            }
        }
    }
}

// ---------------------------------------------------------------------------
// Split-K merge for fc2: out = p0 + p1 + bias + bf16resid (fp32 out, in-place
// over p0).
// ---------------------------------------------------------------------------
__global__ __launch_bounds__(256) void merge_fc2(const float* __restrict__ p0,
                                                 const float* __restrict__ p1,
                                                 const float* __restrict__ bias,
                                                 const bf16* __restrict__ resid,
                                                 float* __restrict__ outp) {
    const int idx = blockIdx.x * 256 + threadIdx.x;
    const int row = idx >> 8, col = (idx & 255) * 4;
    const size_t off = (size_t)row * 1024 + col;
    float4 a = *(const float4*)(p0 + off);
    float4 b = *(const float4*)(p1 + off);
    float4 bs = *(const float4*)(bias + col);
    ushort4 r = *(const ushort4*)((const unsigned short*)resid + off);
    float4 o;
    o.x = a.x + b.x + bs.x + bf2f(r.x);
    o.y = a.y + b.y + bs.y + bf2f(r.y);
    o.z = a.z + b.z + bs.z + bf2f(r.z);
    o.w = a.w + b.w + bs.w + bf2f(r.w);
    *(float4*)(outp + off) = o;
}

// ---------------------------------------------------------------------------
// Flash attention, split-KV x2, NO running max (scores bounded by
// construction). P = exp(s) directly; row-sum l via ones-MFMA.
// Ks/Vs XOR-swizzled; single-buffered (r4: dbuf regressed — TLP covers
// latency); NO setprio (r6: regressed — 4-wave lockstep = m190 regime).
// XCD-chunked grid swizzle (r7: FETCH 71.7 -> 16.4 MB, K/V L2-resident).
// Two-set structure (r10 per-set Ps: +3.7us — grid caps residency, not LDS;
// r11 QBLK=64: +10us — doubles chip-wide staging work). 62us floor is
// per-block staging+exp serial cost; next lever is in-register softmax
// (swapped QK^T, T12) — structural rewrite, future session.
// Writes UNNORMALIZED partial O (bf16) + per-row l (f32).
// ---------------------------------------------------------------------------
__global__ __launch_bounds__(256) void attn_kernel(const bf16* __restrict__ qkv,
                                                   const bf16* __restrict__ vtg,
                                                   bf16* __restrict__ Opart,
                                                   float* __restrict__ Lp) {
    __shared__ __align__(16) bf16 Ks[64 * 64];      // [s][c], swizzled
    __shared__ __align__(16) bf16 Vs[64 * 64];      // [c][s_local], swizzled
    __shared__ __align__(16) bf16 Ps[4][2][16][72]; // per-wave, per-set P tiles
    const int tid  = threadIdx.x;
    const int wave = tid >> 6, lane = tid & 63;
    const int quad = lane >> 4, l16 = lane & 15;
    // XCD-chunked remap of (qt, h, z): nwg = 16*16*4 = 1024, 128 per XCD
    const int f = blockIdx.x + 16 * blockIdx.y + 256 * blockIdx.z;
    const int sid = (f & 7) * 128 + (f >> 3);
    const int qt = sid & 15, h = (sid >> 4) & 15;
    const int zz = sid >> 8;
    const int b = zz >> 1, seg = zz & 1;
    const size_t tok0 = (size_t)b * 2048;
    const int qbase = qt * 128 + wave * 32;

    bf16x8 qf[2][2];
#pragma unroll
    for (int set = 0; set < 2; ++set) {
        const bf16* qp = qkv + (tok0 + qbase + set * 16 + l16) * 3072 + h * 192 + quad * 8;
        qf[set][0] = *(const bf16x8*)(qp);
        qf[set][1] = *(const bf16x8*)(qp + 32);
    }

    // lane l writes LDS row (l>>3), physical chunk (l&7); physical chunk p at
    // row r holds logical chunk p^(r&7)  ->  source loads logical (l&7)^(l>>3)
    const int swc = ((tid & 7) ^ ((tid >> 3) & 7)) * 8;
    const bf16* kg = qkv + (tok0 + (tid >> 3)) * 3072 + h * 192 + 64 + swc;
    const bf16* vg = vtg + ((size_t)(b * 16 + h) * 64 + (tid >> 3)) * 2048 + swc;

    // ones B-frag for row-sum MFMA
    const short oneb = 0x3f80;
    const bf16x8 ones = {oneb, oneb, oneb, oneb, oneb, oneb, oneb, oneb};

    f32x4 o[2][4], l_acc[2];
#pragma unroll
    for (int set = 0; set < 2; ++set) {
        l_acc[set] = (f32x4){0.f, 0.f, 0.f, 0.f};
#pragma unroll
        for (int j = 0; j < 4; ++j) o[set][j] = (f32x4){0.f, 0.f, 0.f, 0.f};
    }

    const int kt0 = seg * 1024;
    for (int kt = kt0; kt < kt0 + 1024; kt += 64) {
        __syncthreads();
        GLLDS16(kg + (size_t)kt * 3072,        &Ks[(wave * 64) * 8]);
        GLLDS16(kg + (size_t)(kt + 32) * 3072, &Ks[(wave * 64 + 256) * 8]);
        GLLDS16(vg + kt,                       &Vs[(wave * 64) * 8]);
        GLLDS16(vg + kt + 32 * 2048,           &Vs[(wave * 64 + 256) * 8]);
        __syncthreads();

        // S = Q K^T ; P = exp(S/8) straight into LDS (C-layout -> A-layout)
#pragma unroll
        for (int j = 0; j < 4; ++j) {
            const int rk = j * 16 + l16;
            const int sw = l16 & 7;             // rk&7 == l16&7 (j*16 ≡ 0 mod 8)
            bf16x8 kb0 = *(const bf16x8*)(&Ks[rk * 64 + ((quad ^ sw) * 8)]);
            bf16x8 kb1 = *(const bf16x8*)(&Ks[rk * 64 + (((quad + 4) ^ sw) * 8)]);
#pragma unroll
            for (int set = 0; set < 2; ++set) {
                f32x4 s4 = (f32x4){0.f, 0.f, 0.f, 0.f};
                s4 = __builtin_amdgcn_mfma_f32_16x16x32_bf16(qf[set][0], kb0, s4, 0, 0, 0);
                s4 = __builtin_amdgcn_mfma_f32_16x16x32_bf16(qf[set][1], kb1, s4, 0, 0, 0);
#pragma unroll
                for (int r = 0; r < 4; ++r)
                    Ps[wave][set][quad * 4 + r][j * 16 + l16] =
                        __float2bfloat16(__expf(s4[r] * 0.125f));
            }
        }
        // O += P V ; l += P 1   (per-wave Ps: same-wave write->read)
#pragma unroll
        for (int kk = 0; kk < 2; ++kk) {
            bf16x8 pf0 = *(const bf16x8*)(&Ps[wave][0][l16][kk * 32 + quad * 8]);
            bf16x8 pf1 = *(const bf16x8*)(&Ps[wave][1][l16][kk * 32 + quad * 8]);
            l_acc[0] = __builtin_amdgcn_mfma_f32_16x16x32_bf16(pf0, ones, l_acc[0], 0, 0, 0);
            l_acc[1] = __builtin_amdgcn_mfma_f32_16x16x32_bf16(pf1, ones, l_acc[1], 0, 0, 0);
#pragma unroll
            for (int j = 0; j < 4; ++j) {
                const int rv = j * 16 + l16;
                bf16x8 vf = *(const bf16x8*)(&Vs[rv * 64 + (((kk * 4 + quad) ^ (l16 & 7)) * 8)]);
                o[0][j] = __builtin_amdgcn_mfma_f32_16x16x32_bf16(pf0, vf, o[0][j], 0, 0, 0);
                o[1][j] = __builtin_amdgcn_mfma_f32_16x16x32_bf16(pf1, vf, o[1][j], 0, 0, 0);
            }
        }
    }
    // write unnormalized partials + l
    const size_t segoff = (size_t)seg * 4096;
#pragma unroll
    for (int set = 0; set < 2; ++set)
#pragma unroll
        for (int j = 0; j < 4; ++j)
#pragma unroll
            for (int r = 0; r < 4; ++r) {
                int row = qbase + set * 16 + quad * 4 + r;
                Opart[(segoff + tok0 + row) * 1024 + h * 64 + j * 16 + l16] =
                    __float2bfloat16(o[set][j][r]);
            }
    if (l16 == 0) {
#pragma unroll
        for (int set = 0; set < 2; ++set)
#pragma unroll
            for (int r = 0; r < 4; ++r) {
                int row = qbase + set * 16 + quad * 4 + r;
                Lp[(segoff + tok0 + row) * 16 + h] = l_acc[set][r];
            }
    }
}

// ---------------------------------------------------------------------------
// Merge two KV-segments: out = (O0 + O1) / (l0 + l1).
// ---------------------------------------------------------------------------
__global__ __launch_bounds__(256) void merge_kernel(const bf16* __restrict__ Opart,
                                                    const float* __restrict__ Lp,
                                                    bf16* __restrict__ outp) {
    const int idx = blockIdx.x * 256 + threadIdx.x;
    const int c4 = idx & 15, h = (idx >> 4) & 15, gt = idx >> 8;
    const size_t li0 = (size_t)gt * 16 + h, li1 = li0 + 4096 * 16;
    float inv = 1.0f / (Lp[li0] + Lp[li1]);
    const size_t off = (size_t)gt * 1024 + h * 64 + c4 * 4;
    ushort4 a = *(const ushort4*)((const unsigned short*)Opart + off);
    ushort4 bb = *(const ushort4*)((const unsigned short*)Opart + off + (size_t)4096 * 1024);
    float va[4] = {bf2f(a.x), bf2f(a.y), bf2f(a.z), bf2f(a.w)};
    float vb[4] = {bf2f(bb.x), bf2f(bb.y), bf2f(bb.z), bf2f(bb.w)};
    unsigned short res[4];
#pragma unroll
    for (int e = 0; e < 4; ++e) {
        bf16 o = __float2bfloat16((va[e] + vb[e]) * inv);
        res[e] = *(unsigned short*)&o;
    }
    *(ushort4*)((unsigned short*)outp + off) = make_ushort4(res[0], res[1], res[2], res[3]);
}

// ---------------------------------------------------------------------------
// Workspace map (64 MB, lifetime-aliased; launch order t0..t6):
//  [ 0, 8)  wfcT      t0 -> t5 ; fc2 split-K partial1 [0,16) t6 -> t6.5
//  [ 8,16)  ln1 out   t0 -> t1 ; wprojT [8,10) t1.6->t3 ; Lp [10,10.5) t2->t2.5 ; ln2 t4->t5
//  [16,22)  wqkvT     t0 -> t1
//  [16,24)  vtg       t1.5 -> t2 ; attn-out t2.5 -> t3 ; fcact(lo) t5->t6
//  [24,48)  qkvb      t1 -> t2 ; fcact(hi) t5 -> t6
//  [48,64)  Opart     t2 -> t2.5 ; wfc2T [48,56) t2.6->t6 ; x1 bf16 [56,64) t3->t6.5
// ---------------------------------------------------------------------------
extern "C" void kernel_launch(void* const* d_in, const int* in_sizes, int n_in,
                              void* d_out, int out_size, void* d_ws, size_t ws_size,
                              hipStream_t stream) {
    const float* x      = (const float*)d_in[0];
    const float* ln1_g  = (const float*)d_in[1];
    const float* ln1_b  = (const float*)d_in[2];
    const float* qkv_w  = (const float*)d_in[3];
    const float* qkv_b  = (const float*)d_in[4];
    const float* proj_w = (const float*)d_in[5];
    const float* proj_b = (const float*)d_in[6];
    const float* ln2_g  = (const float*)d_in[7];
    const float* ln2_b  = (const float*)d_in[8];
    const float* fc_w   = (const float*)d_in[9];
    const float* fc_b   = (const float*)d_in[10];
    const float* fc2_w  = (const float*)d_in[11];
    const float* fc2_b  = (const float*)d_in[12];
    float* outp = (float*)d_out;

    char* ws = (char*)d_ws;
    const size_t MB = 1024 * 1024;
    bf16*  wfcT   = (bf16*)(ws + 0 * MB);
    float* part1  = (float*)(ws + 0 * MB);   // fc2 split-K partial (16 MB, dead wfcT+lnbuf)
    bf16*  lnbuf  = (bf16*)(ws + 8 * MB);    // ln1 / ln2 slab
    bf16*  wprojT = (bf16*)(ws + 8 * MB);
    float* Lp     = (float*)(ws + 10 * MB);
    bf16*  wqkvT  = (bf16*)(ws + 16 * MB);
    bf16*  vtg    = (bf16*)(ws + 16 * MB);
    bf16*  attnout= (bf16*)(ws + 16 * MB);
    bf16*  fcact  = (bf16*)(ws + 16 * MB);   // [16,48)
    bf16*  qkvb   = (bf16*)(ws + 24 * MB);
    bf16*  Opart  = (bf16*)(ws + 48 * MB);
    bf16*  wfc2T  = (bf16*)(ws + 48 * MB);
    bf16*  x1     = (bf16*)(ws + 56 * MB);

    // t0: qkv+fc transposes (ONE dispatch) + ln1
    transpose2_f2b<<<dim3(96 + 128, 32), 256, 0, stream>>>(qkv_w, wqkvT, 3072, 96,
                                                           fc_w,  wfcT,  4096, 1024);
    ln_kernel<float><<<4096, 256, 0, stream>>>(x, ln1_g, ln1_b, lnbuf);
    // t1: qkv = ln1 @ qkv_w + b
    gemm_kernel<0, 128, false><<<dim3(24, 32), 256, 0, stream>>>(lnbuf, wqkvT, qkv_b, nullptr, qkvb, 4096, 3072, 1024);
    // t1.5: V pre-transpose (overwrites wqkvT region — dead)
    vtrans_kernel<<<dim3(64, 2, 32), 256, 0, stream>>>(qkvb, vtg);
    // t1.6: proj transpose (into dead ln1 region)
    transpose_f2b<<<dim3(32, 32), 256, 0, stream>>>(proj_w, wprojT, 1024, 1024);
    // t2: attention split-KV x2 (1024 blocks, XCD-chunked)
    attn_kernel<<<dim3(16, 16, 4), 256, 0, stream>>>(qkvb, vtg, Opart, Lp);
    // t2.5: merge segments -> attn-out (overwrites vtg — dead)
    merge_kernel<<<4096, 256, 0, stream>>>(Opart, Lp, attnout);
    // t2.6: fc2 transpose (into dead Opart region)
    transpose_f2b<<<dim3(32, 128), 256, 0, stream>>>(fc2_w, wfc2T, 4096, 1024);
    // t3: x1 = x + attn @ proj_w + b   (BM=64: 512 blocks, XCD-swizzled)
    gemm_kernel<2, 64, true><<<dim3(8, 64), 256, 0, stream>>>(attnout, wprojT, proj_b, x, x1, 4096, 1024, 1024);
    // t4: ln2(x1)
    ln_kernel<bf16><<<4096, 256, 0, stream>>>(x1, ln2_g, ln2_b, lnbuf);
    // t5: fcact = gelu(ln2 @ fc_w + b)
    gemm_kernel<1, 128, false><<<dim3(32, 32), 256, 0, stream>>>(lnbuf, wfcT, fc_b, nullptr, fcact, 4096, 4096, 1024);
    // t6: split-K=2 fc2 partials: z=0 -> outp, z=1 -> part1  (1024 blocks, XCD-swizzled)
    gemm_kernel<4, 64, true><<<dim3(8, 64, 2), 256, 0, stream>>>(fcact, wfc2T, nullptr, part1, outp, 4096, 1024, 4096);
    // t6.5: out = p0 + p1 + bias + x1
    merge_fc2<<<4096, 256, 0, stream>>>(outp, part1, fc2_b, x1, outp);
}